// Round 6
// baseline (218.822 us; speedup 1.0000x reference)
//
#include <hip/hip_runtime.h>

namespace {
constexpr int TOK = 8192;
constexpr int DIM = 4096;
constexpr int NE  = 64;
constexpr int TB  = 128;          // tokens per gemm tile (8 waves x 16)
constexpr int KS  = 4;            // split-K factor
constexpr int KR  = DIM / KS;     // 1024 k per block
constexpr int NKS = KR / 32;      // 32 K32-steps per block
constexpr int NRND = NKS / 8;     // 4 staging rounds (8 steps each)
constexpr int NT  = TOK / TB;     // 64 token tiles
constexpr int GB  = 64;           // tokens per gating chunk
constexpr int NCH = TOK / GB;     // 128 chunks
}

typedef _Float16 f16x8 __attribute__((ext_vector_type(8)));
typedef float    f32x4 __attribute__((ext_vector_type(4)));

// ---------------------------------------------------------------------------
// Split-K GEMM, W packed inline. 256 blocks (NT*KS) x 512 threads, 1 block/CU.
// Wave w: tokens [t0+w*16,+16) x 64 experts. Per 8-step round, wave pair
// (et, et+4's wave) packs W fp32 -> hi/lo fp16 fragments into LDS
// (contiguous ds_write_b128, conflict-free); A streamed from global with a
// depth-2 register pipeline. logits ~= Ahi*Bhi + Ahi*Blo + Alo*Bhi.
// ---------------------------------------------------------------------------
__global__ __launch_bounds__(512, 4) void gemm_split(
    const float* __restrict__ A, const float* __restrict__ W,
    float* __restrict__ partial) {
  // 8 chunks (fmt*4+et) x 8 steps x 64 lanes x 8 halves = 64 KB
  __shared__ _Float16 sB[8 * 8 * 64 * 8];

  const int bid  = blockIdx.x;
  const int tile = bid & (NT - 1);
  const int ks   = bid / NT;
  const int t0   = tile * TB;
  const int tid  = threadIdx.x;
  const int w    = tid >> 6;        // wave 0..7
  const int lane = tid & 63;
  const int col  = lane & 15;
  const int quad = lane >> 4;

  // staging role: this wave packs expert tile (w&3), steps [s0, s0+4)
  const int etw = w & 3;
  const int s0  = (w >> 2) * 4;
  const float* Wp = W + (size_t)(etw * 16 + col) * DIM + ks * KR + quad * 8;

  // this lane's A row: token t0 + w*16 + col, k = ks*KR + quad*8
  const float* Ap = A + (size_t)(t0 + w * 16 + col) * DIM + ks * KR + quad * 8;

  f32x4 acc[4];
#pragma unroll
  for (int et = 0; et < 4; ++et) acc[et] = (f32x4)0.0f;

  // A pipeline prologue: steps 0 and 1 in flight
  float4 a0  = *(const float4*)(Ap);
  float4 a1  = *(const float4*)(Ap + 4);
  float4 a0n = *(const float4*)(Ap + 32);
  float4 a1n = *(const float4*)(Ap + 36);

  for (int rnd = 0; rnd < NRND; ++rnd) {
    if (rnd) __syncthreads();    // previous round's sB reads done
    // pack this wave's W slab: 4 steps x (16 e x 32 k), hi+lo
#pragma unroll
    for (int s = s0; s < s0 + 4; ++s) {
      const float4 w0 = *(const float4*)(Wp + (rnd * 8 + s) * 32);
      const float4 w1 = *(const float4*)(Wp + (rnd * 8 + s) * 32 + 4);
      const float wv[8] = {w0.x, w0.y, w0.z, w0.w, w1.x, w1.y, w1.z, w1.w};
      f16x8 hi, lo;
#pragma unroll
      for (int j = 0; j < 8; ++j) {
        const _Float16 h = (_Float16)wv[j];
        hi[j] = h;
        lo[j] = (_Float16)(wv[j] - (float)h);
      }
      *(f16x8*)(sB + ((etw * 8 + s) << 9) + lane * 8) = hi;
      *(f16x8*)(sB + (((4 + etw) * 8 + s) << 9) + lane * 8) = lo;
    }
    __syncthreads();             // staging complete

    for (int s = 0; s < 8; ++s) {
      const int it = rnd * 8 + s;
      // issue A(it+2)
      float4 a0nn, a1nn;
      if (it + 2 < NKS) {
        a0nn = *(const float4*)(Ap + (it + 2) * 32);
        a1nn = *(const float4*)(Ap + (it + 2) * 32 + 4);
      }
      // convert A fp32 -> fp16 hi/lo in registers
      const float av[8] = {a0.x, a0.y, a0.z, a0.w, a1.x, a1.y, a1.z, a1.w};
      f16x8 ah, al;
#pragma unroll
      for (int j = 0; j < 8; ++j) {
        const _Float16 h = (_Float16)av[j];
        ah[j] = h;
        al[j] = (_Float16)(av[j] - (float)h);
      }
#pragma unroll
      for (int et = 0; et < 4; ++et) {
        const f16x8 bh = *(const f16x8*)(sB + ((et * 8 + s) << 9) + lane * 8);
        const f16x8 bl =
            *(const f16x8*)(sB + (((4 + et) * 8 + s) << 9) + lane * 8);
        acc[et] = __builtin_amdgcn_mfma_f32_16x16x32_f16(ah, bh, acc[et], 0, 0, 0);
        acc[et] = __builtin_amdgcn_mfma_f32_16x16x32_f16(ah, bl, acc[et], 0, 0, 0);
        acc[et] = __builtin_amdgcn_mfma_f32_16x16x32_f16(al, bh, acc[et], 0, 0, 0);
      }
      a0 = a0n; a1 = a1n; a0n = a0nn; a1n = a1nn;
    }
  }

  // epilogue: C/D col=lane&15 (expert low), row=quad*4+r (token)
  float* P = partial + (size_t)ks * TOK * NE;
  const int tb = t0 + w * 16 + quad * 4;
#pragma unroll
  for (int et = 0; et < 4; ++et) {
    const int e = et * 16 + col;
#pragma unroll
    for (int r = 0; r < 4; ++r)
      P[(size_t)(tb + r) * NE + e] = acc[et][r];
  }
}

// ---------------------------------------------------------------------------
// Gating: 128 blocks x 256 threads, 64 tokens each; 4 threads per token.
// Sum split-K partials -> logits; argmax (first-occurrence) / softmax /
// rank + histogram; me partials per chunk.
// ---------------------------------------------------------------------------
__global__ __launch_bounds__(256) void gating(
    const float* __restrict__ partial, float* __restrict__ out,
    int* __restrict__ idx_int, int* __restrict__ rankp,
    int* __restrict__ hist, float* __restrict__ me_part) {
  __shared__ float L[GB * 65];     // 64 tokens x 64 logits, stride 65
  __shared__ float pm[4][GB];
  __shared__ int   pi[4][GB];
  __shared__ float ps[4][GB];
  __shared__ float mep[4][NE];
  __shared__ float mx[GB];
  __shared__ float dninv[GB];
  __shared__ int   eid[GB];
  const int b = blockIdx.x, tid = threadIdx.x;
  const int t = tid & 63, q = tid >> 6;
  const size_t base = (size_t)b * GB * NE;

  // load + sum partials: 4 float4 per thread
#pragma unroll
  for (int j = 0; j < 4; ++j) {
    const int i4 = tid + 256 * j;              // [0,1024): (token, e-group of 4)
    const int tt = i4 >> 4, e4 = (i4 & 15) * 4;
    f32x4 s = (f32x4)0.0f;
#pragma unroll
    for (int k = 0; k < KS; ++k) {
      const f32x4 v = *(const f32x4*)(partial + (size_t)k * TOK * NE + base +
                                      (size_t)tt * NE + e4);
      s += v;
    }
    *(f32x4*)(L + tt * 65 + e4) = s;
  }
  __syncthreads();

  {  // partial argmax over 16 experts (first-occurrence within range)
    float m = -3.0e38f; int bi = q * 16;
#pragma unroll
    for (int e = q * 16; e < q * 16 + 16; ++e) {
      const float v = L[t * 65 + e];
      if (v > m) { m = v; bi = e; }
    }
    pm[q][t] = m; pi[q][t] = bi;
  }
  __syncthreads();
  if (tid < GB) {  // combine (ascending q keeps first occurrence)
    float m = -3.0e38f; int bi = 0;
#pragma unroll
    for (int qq = 0; qq < 4; ++qq) {
      if (pm[qq][tid] > m) { m = pm[qq][tid]; bi = pi[qq][tid]; }
    }
    mx[tid] = m; eid[tid] = bi;
    const int gt = b * GB + tid;
    out[1 + gt] = (float)bi;     // indices1_s
    idx_int[gt] = bi;
  }
  __syncthreads();
  {  // partial expf sums
    const float m = mx[t];
    float s = 0.0f;
#pragma unroll
    for (int e = q * 16; e < q * 16 + 16; ++e) s += __expf(L[t * 65 + e] - m);
    ps[q][t] = s;
  }
  __syncthreads();
  if (tid < GB) {
    const float inv = 1.0f / (ps[0][tid] + ps[1][tid] + ps[2][tid] + ps[3][tid]);
    dninv[tid] = inv;
    out[1 + 2 * TOK + b * GB + tid] = inv;   // gates1_s = softmax at argmax
  }
  __syncthreads();
  {  // me partials: thread (e = t, quarter q) over 16 tokens
    const int e = t;
    float s = 0.0f;
#pragma unroll
    for (int tt = q * 16; tt < q * 16 + 16; ++tt)
      s += __expf(L[tt * 65 + e] - mx[tt]) * dninv[tt];
    mep[q][e] = s;
  }
  __syncthreads();
  if (tid < GB) {  // rank within chunk + chunk histogram
    const int e = eid[tid];
    int r = 0;
    for (int j = 0; j < tid; ++j) r += (eid[j] == e) ? 1 : 0;
    rankp[b * GB + tid] = r;
    int c = 0;
    for (int t2 = 0; t2 < GB; ++t2) c += (eid[t2] == tid) ? 1 : 0;
    hist[b * NE + tid] = c;
  } else if (tid < 2 * GB) {
    const int e = tid - GB;
    me_part[b * NE + e] = mep[0][e] + mep[1][e] + mep[2][e] + mep[3][e];
  }
}

// ---------------------------------------------------------------------------
// Finalize: 1 block x 1024 threads. 16-segment per-expert exclusive scan over
// chunk hists -> locations; ce + me reduce -> l_aux.
// ---------------------------------------------------------------------------
__global__ __launch_bounds__(1024) void finalize(
    const int* __restrict__ idx_int, const int* __restrict__ rankp,
    const int* __restrict__ hist, const float* __restrict__ me_part,
    float* __restrict__ out) {
  __shared__ int   H[NCH * NE];    // 32 KB
  __shared__ int   SEG[16 * NE];
  __shared__ float MEp[16 * NE];
  __shared__ float CE[NE];
  const int tid = threadIdx.x;
  const int e = tid & 63, seg = tid >> 6;   // 16 segments x 8 chunks

  for (int j = tid; j < NCH * NE; j += 1024) H[j] = hist[j];
  {
    float s = 0.0f;
    for (int c = seg * 8; c < seg * 8 + 8; ++c) s += me_part[c * NE + e];
    MEp[seg * NE + e] = s;
  }
  __syncthreads();
  {
    int hs = 0;
    for (int c = seg * 8; c < seg * 8 + 8; ++c) hs += H[c * NE + e];
    SEG[seg * NE + e] = hs;
  }
  __syncthreads();
  if (tid < NE) {  // exclusive scan of 16 segment sums per expert
    int run = 0;
    for (int s2 = 0; s2 < 16; ++s2) {
      const int v = SEG[s2 * NE + tid];
      SEG[s2 * NE + tid] = run;
      run += v;
    }
    CE[tid] = (float)run;  // ce[e]
  }
  __syncthreads();
  {  // per (e,seg): exclusive scan within segment
    int run = SEG[seg * NE + e];
    for (int c = seg * 8; c < seg * 8 + 8; ++c) {
      const int v = H[c * NE + e];
      H[c * NE + e] = run;
      run += v;
    }
  }
  if (tid < 64) {  // l_aux
    float me = 0.0f;
#pragma unroll
    for (int s2 = 0; s2 < 16; ++s2) me += MEp[s2 * NE + tid];
    float p = me * CE[tid];
#pragma unroll
    for (int off = 32; off > 0; off >>= 1) p += __shfl_down(p, off);
    if (tid == 0) out[0] = p * ((float)NE / ((float)TOK * (float)TOK));
  }
  __syncthreads();
#pragma unroll
  for (int i = tid; i < TOK; i += 1024) {  // locations1_s
    const int ex = idx_int[i];
    out[1 + TOK + i] = (float)(H[(i >> 6) * NE + ex] + rankp[i]);
  }
}

extern "C" void kernel_launch(void* const* d_in, const int* in_sizes, int n_in,
                              void* d_out, int out_size, void* d_ws, size_t ws_size,
                              hipStream_t stream) {
  const float* A = (const float*)d_in[0];   // [8192, 4096] fp32
  const float* W = (const float*)d_in[1];   // [64, 4096] fp32
  float* out = (float*)d_out;               // 1 + 8192*3 floats
  char* ws = (char*)d_ws;

  float* partial = (float*)ws;                                  // 8 MB
  size_t off = (size_t)KS * TOK * NE * sizeof(float);
  float* me_part = (float*)(ws + off);  off += (size_t)NCH * NE * sizeof(float);
  int* idx_int = (int*)(ws + off);      off += (size_t)TOK * sizeof(int);
  int* rankp   = (int*)(ws + off);      off += (size_t)TOK * sizeof(int);
  int* hist    = (int*)(ws + off);

  hipLaunchKernelGGL(gemm_split, dim3(NT * KS), dim3(512), 0, stream,
                     A, W, partial);
  hipLaunchKernelGGL(gating, dim3(NCH), dim3(256), 0, stream, partial, out,
                     idx_int, rankp, hist, me_part);
  hipLaunchKernelGGL(finalize, dim3(1), dim3(1024), 0, stream, idx_int, rankp,
                     hist, me_part, out);
}